// Round 5
// baseline (1058.254 us; speedup 1.0000x reference)
//
#include <hip/hip_runtime.h>
#include <cfloat>

#define NB  32
#define ND  256
#define NK  512
#define NHW 4096
#define PX  16
#define ZSTR (ND + 4)   // 260; 260*4B = 65*16B -> float4-aligned rows

// C declared int64 in the reference; detect storage width on device.
__device__ __forceinline__ int loadC(const int* __restrict__ C, int b) {
  int orodd = 0;
#pragma unroll
  for (int i = 1; i < 32; i += 2) orodd |= C[i];
  return (orodd == 0) ? C[2 * b] : C[b];
}

// np.sum pairwise block (n=128, contiguous), operating on fl(z*z):
// r[0..7]=a[0..7]; 15x: r[j]+=a[8i+j]; ((r0+r1)+(r2+r3))+((r4+r5)+(r6+r7))
__device__ __forceinline__ float pwsq128(const float* __restrict__ a) {
  float r[8];
#pragma unroll
  for (int j = 0; j < 8; ++j) r[j] = __fmul_rn(a[j], a[j]);
  for (int i = 8; i < 128; i += 8)
#pragma unroll
    for (int j = 0; j < 8; ++j)
      r[j] = __fadd_rn(r[j], __fmul_rn(a[i + j], a[i + j]));
  return __fadd_rn(
      __fadd_rn(__fadd_rn(r[0], r[1]), __fadd_rn(r[2], r[3])),
      __fadd_rn(__fadd_rn(r[4], r[5]), __fadd_rn(r[6], r[7])));
}

// Fused: np-f32-replica scoring + argmin + gather + transpose-write. No d_ws.
__global__ __launch_bounds__(256, 1) void k_fused(
    const float* __restrict__ z, const int* __restrict__ Cc,
    const float* __restrict__ w, float* __restrict__ out) {
  __shared__ float Zs[PX][ZSTR];
  __shared__ float Ssh[PX];
  __shared__ float SV[4][PX];
  __shared__ int   SI[4][PX];
  __shared__ int   KB[PX];

  int blk = blockIdx.x;               // 8192 = 32 batches x 256 tiles
  int b   = blk >> 8;
  int n0  = (blk & 255) * PX;
  int c   = loadC(Cc, b);
  int t   = threadIdx.x;
  int lane = t & 63, wv = t >> 6;

  // stage z tile [16 px][256 d]
  {
    int px = t & 15, tg = t >> 4;
    const float* zp = z + (size_t)b * ND * NHW + n0 + px;
#pragma unroll
    for (int j = 0; j < 16; ++j) {
      int d = tg * 16 + j;
      Zs[px][d] = zp[(size_t)d * NHW];
    }
  }
  __syncthreads();

  // S[px] = np.sum(z*z) pairwise replica: pw(0:128) + pw(128:256)
  if (t < PX)
    Ssh[t] = __fadd_rn(pwsq128(&Zs[t][0]), pwsq128(&Zs[t][128]));
  __syncthreads();

  // ---- scoring: thread t owns codes k=t and k=t+256 for all 16 pixels ----
  float bv[PX]; int bi[PX];
  float XA[PX];
#pragma unroll
  for (int kk = 0; kk < 2; ++kk) {
    int k = t + kk * 256;
    const float* er = w + ((size_t)c * NK + k) * ND;
    float P0[PX], P1[PX], P2[PX], P3[PX];
#pragma unroll
    for (int p = 0; p < PX; ++p) { P0[p]=0.f; P1[p]=0.f; P2[p]=0.f; P3[p]=0.f; }

    for (int ch = 0; ch < 16; ++ch) {   // 16 elements per chunk
      const float* eb = er + ch * 16;
      float4 e0 = *(const float4*)(eb + 0);
      float4 e1 = *(const float4*)(eb + 4);
      float4 e2 = *(const float4*)(eb + 8);
      float4 e3 = *(const float4*)(eb + 12);
#pragma unroll
      for (int p = 0; p < PX; ++p) {
        const float* zb = &Zs[p][ch * 16];
        float4 z0 = *(const float4*)(zb + 0);
        float4 z1 = *(const float4*)(zb + 4);
        float4 z2 = *(const float4*)(zb + 8);
        float4 z3 = *(const float4*)(zb + 12);
        // einsum npyv replica: per SSE lane j, chained adds in order
        // d=+12+j, +8+j, +4+j, +0+j (reversed 4x unroll), mul/add unfused.
        P0[p] = __fadd_rn(P0[p], __fmul_rn(z3.x, e3.x));
        P0[p] = __fadd_rn(P0[p], __fmul_rn(z2.x, e2.x));
        P0[p] = __fadd_rn(P0[p], __fmul_rn(z1.x, e1.x));
        P0[p] = __fadd_rn(P0[p], __fmul_rn(z0.x, e0.x));
        P1[p] = __fadd_rn(P1[p], __fmul_rn(z3.y, e3.y));
        P1[p] = __fadd_rn(P1[p], __fmul_rn(z2.y, e2.y));
        P1[p] = __fadd_rn(P1[p], __fmul_rn(z1.y, e1.y));
        P1[p] = __fadd_rn(P1[p], __fmul_rn(z0.y, e0.y));
        P2[p] = __fadd_rn(P2[p], __fmul_rn(z3.z, e3.z));
        P2[p] = __fadd_rn(P2[p], __fmul_rn(z2.z, e2.z));
        P2[p] = __fadd_rn(P2[p], __fmul_rn(z1.z, e1.z));
        P2[p] = __fadd_rn(P2[p], __fmul_rn(z0.z, e0.z));
        P3[p] = __fadd_rn(P3[p], __fmul_rn(z3.w, e3.w));
        P3[p] = __fadd_rn(P3[p], __fmul_rn(z2.w, e2.w));
        P3[p] = __fadd_rn(P3[p], __fmul_rn(z1.w, e1.w));
        P3[p] = __fadd_rn(P3[p], __fmul_rn(z0.w, e0.w));
      }
    }
#pragma unroll
    for (int p = 0; p < PX; ++p) {
      // horizontal: SSE3 hadd tree (P0+P1)+(P2+P3)
      float G = __fadd_rn(__fadd_rn(P0[p], P1[p]), __fadd_rn(P2[p], P3[p]));
      // dist = fl(S - fl(2G)); ||e||^2 term absorbed (< ulp/2 at |dist|>=128)
      float X = __fadd_rn(Ssh[p], __fmul_rn(-2.0f, G));
      if (kk == 0) XA[p] = X;
      else {
        if (X < XA[p]) { bv[p] = X;     bi[p] = t + 256; }
        else           { bv[p] = XA[p]; bi[p] = t; }
      }
    }
  }

  // ---- per-pixel argmin across threads (ties -> lowest k) ----
#pragma unroll
  for (int p = 0; p < PX; ++p) {
    float v = bv[p]; int i = bi[p];
#pragma unroll
    for (int off = 32; off; off >>= 1) {
      float ov = __shfl_down(v, off);
      int   oi = __shfl_down(i, off);
      if (ov < v || (ov == v && oi < i)) { v = ov; i = oi; }
    }
    if (lane == 0) { SV[wv][p] = v; SI[wv][p] = i; }
  }
  __syncthreads();
  if (t < PX) {
    float v = SV[0][t]; int i = SI[0][t];
#pragma unroll
    for (int wv2 = 1; wv2 < 4; ++wv2) {
      float ov = SV[wv2][t]; int oi = SI[wv2][t];
      if (ov < v || (ov == v && oi < i)) { v = ov; i = oi; }
    }
    KB[t] = i;
  }
  __syncthreads();

  // ---- gather + transpose-write both outputs ----
  {
    int px = t & 15, tg = t >> 4;
    int kidx = KB[px];
    const float* er = w + ((size_t)c * NK + kidx) * ND;
    const size_t OUT2 = (size_t)NB * ND * NHW;
    size_t base = (size_t)b * ND * NHW + n0 + px;
#pragma unroll
    for (int j = 0; j < 16; ++j) {
      int d = tg * 16 + j;
      float q  = er[d];
      float zv = Zs[px][d];
      // replicate np out0 = fl(z + fl(q - z)); out1 = q exactly
      out[base + (size_t)d * NHW]        = __fadd_rn(zv, __fsub_rn(q, zv));
      out[base + (size_t)d * NHW + OUT2] = q;
    }
  }
}

extern "C" void kernel_launch(void* const* d_in, const int* in_sizes, int n_in,
                              void* d_out, int out_size, void* d_ws, size_t ws_size,
                              hipStream_t stream) {
  const float* z = (const float*)d_in[0];
  const int*   C = (const int*)d_in[1];
  const float* w = (const float*)d_in[2];
  float* out = (float*)d_out;
  k_fused<<<NB * (NHW / PX), 256, 0, stream>>>(z, C, w, out);
}